// Round 2
// baseline (3139.844 us; speedup 1.0000x reference)
//
#include <hip/hip_runtime.h>
#include <stdint.h>

// 3-layer LSTM (H=64, B=256, S=4096, DIN=1) + linear head.
// One block/batch element; 768 thr = 3 groups of 256 (group = layer), skewed
// pipeline (tick T: l0@T, l1@T-1, l2@T-2, y@T-3).
//
// R9: matvec engine moved from v_dot2 (VALU) to MFMA 16x16x32 f16 (matrix
// pipe). R7/R8 proved the RA spills per-thread weight vectors to AGPR
// (VGPR_Count=48 with 64 u32 needed -> ~64 accvgpr_read/tick/thread, the
// VALUBusy~67% excess). As MFMA A-fragments the weights live in AGPRs
// NATIVELY (zero per-tick moves), the K-reduce happens inside MFMA (DPP
// butterfly deleted), and 64 dots/thread/tick -> 16 MFMA/wave/tick.
// Row packing (prep kernel) chosen so D row p = gate (p&3) of unit (p>>2):
// each wave's D col-0 values (lanes 0/16/32/48) are exactly the gate values
// its own 64 threads consume -> intra-wave LDS bounce, no extra barrier.
// B-frag = h broadcast read (same-addr ds_read_b128, conflict-free);
// garbage in D cols 1..15 is never read.

#define SQ 4096
#define HH 64
#define NB 256

typedef _Float16 h2    __attribute__((ext_vector_type(2)));
typedef _Float16 f16x8 __attribute__((ext_vector_type(8)));
typedef float    f32x4 __attribute__((ext_vector_type(4)));

template<int CTRL>
__device__ __forceinline__ float fdpp(float v) {
    return __builtin_bit_cast(float,
        __builtin_amdgcn_mov_dpp(__builtin_bit_cast(int, v), CTRL, 0xF, 0xF, true));
}
// quad_perm encodings: xor1=(1,0,3,2), xor2=(2,3,0,1), xor3=(3,2,1,0)
#define DPP_XOR1 0xB1
#define DPP_XOR2 0x4E
#define DPP_XOR3 0x1B
#define DPP_ROR4 0x124
#define DPP_ROR8 0x128

__device__ __forceinline__ float frcp(float x)  { return __builtin_amdgcn_rcpf(x); }
__device__ __forceinline__ float fexp2(float x) { return __builtin_amdgcn_exp2f(x); }

__device__ __forceinline__ void pin4(uint4& r) {
    asm volatile("" : "+v"(r.x), "+v"(r.y), "+v"(r.z), "+v"(r.w));
}

__device__ __forceinline__ f32x4 mm(uint4 wv, uint4 bv, f32x4 c) {
    return __builtin_amdgcn_mfma_f32_16x16x32_f16(
        __builtin_bit_cast(f16x8, wv), __builtin_bit_cast(f16x8, bv), c, 0, 0, 0);
}

// ---- prep: fp32 weights -> MFMA A-fragments (packed fp16 pairs).
// ws regions: grp0 [0,8192) u32 (Whh0, KT=2); grp1 [8192,24576) (Wih1|Whh1,
// KT=4); grp2 [24576,40960) (Wih2|Whh2, KT=4).
// Within region: r = (((w*4 + t)*KT + kt)*64 + l)*4 + j.
// Fragment (w,t,kt,lane l, pair j) = A_packed[row16 = l&15,
//   kloc = (l>>4)*8 + 2j (+1)] of M-tile (w,t), K-tile kt.
// Packed row p = 64w + 16t + (l&15); original gate row = (p&3)*64 + (p>>2)
// (so D row p = gate p&3 of unit p>>2). kt<2 -> Wih cols, kt>=2 -> Whh cols.
__global__ __launch_bounds__(256)
void prep_weights(const float* __restrict__ Whh0, const float* __restrict__ Wih1,
                  const float* __restrict__ Whh1, const float* __restrict__ Wih2,
                  const float* __restrict__ Whh2, uint32_t* __restrict__ ws)
{
    const int idx = blockIdx.x * 256 + threadIdx.x;   // 0..40959
    int r, KT;
    const float *Wi = nullptr, *Wh;
    if (idx < 8192)       { r = idx;         KT = 2; Wh = Whh0; }
    else if (idx < 24576) { r = idx - 8192;  KT = 4; Wi = Wih1; Wh = Whh1; }
    else                  { r = idx - 24576; KT = 4; Wi = Wih2; Wh = Whh2; }
    const int j   = r & 3;
    const int l   = (r >> 2) & 63;
    const int rem = r >> 8;
    const int kt  = rem & (KT - 1);
    const int tw  = rem / KT;
    const int t   = tw & 3;
    const int w   = tw >> 2;
    const int p    = w * 64 + t * 16 + (l & 15);
    const int orow = (p & 3) * 64 + (p >> 2);
    const int kk   = (l >> 4) * 8 + 2 * j;
    const float* M; int col;
    if (KT == 2)     { M = Wh; col = kt * 32 + kk; }
    else if (kt < 2) { M = Wi; col = kt * 32 + kk; }
    else             { M = Wh; col = (kt - 2) * 32 + kk; }
    h2 tt;
    tt[0] = (_Float16)M[orow * HH + col];
    tt[1] = (_Float16)M[orow * HH + col + 1];
    ws[idx] = __builtin_bit_cast(uint32_t, tt);
}

__global__ __launch_bounds__(768)
__attribute__((amdgpu_waves_per_eu(1, 3)))
void lstm3_fused(
    const float* __restrict__ x,
    const float* __restrict__ Wih0,
    const float* __restrict__ bih0, const float* __restrict__ bhh0,
    const float* __restrict__ bih1, const float* __restrict__ bhh1,
    const float* __restrict__ bih2, const float* __restrict__ bhh2,
    const float* __restrict__ Wlin, const float* __restrict__ blin,
    const uint32_t* __restrict__ wpk,
    float* __restrict__ out)
{
    const int b   = blockIdx.x;
    const int tid = threadIdx.x;
    const int grp = tid >> 8;          // layer 0,1,2
    const int k   = tid & 255;
    const int u   = k >> 2;            // hidden unit
    const int qt  = k & 3;             // gate index
    const int row = qt * HH + u;       // this thread's gate row
    const int w   = k >> 6;            // wave within group
    const int l   = k & 63;            // lane
    const int q   = l >> 4;            // 16-lane sub-group
    const bool lz = (l & 15) == 0;     // D col-0 lane

    __shared__ __align__(16) float xrow[SQ];
    __shared__ __align__(16) uint4 hbf[2][3][8];   // [buf][layer][8x uint4 = 64 fp16]
    __shared__ __align__(16) float ybuf[2][16];    // per-row head partials
    __shared__ __align__(16) float gbuf[3][256];   // gate redistribution (intra-wave)

    for (int i = tid; i < SQ; i += 768) xrow[i] = x[b * SQ + i];
    if (tid < 48) ((uint4*)hbf)[tid] = make_uint4(0, 0, 0, 0);
    if (tid < 32) ((float*)ybuf)[tid] = 0.f;

    // ---- weights: MFMA A-fragments from workspace ----
    const int gbase = (grp == 0) ? 0 : (grp == 1) ? 8192 : 24576;
    const int KT    = (grp == 0) ? 2 : 4;
    const uint32_t* wbp = wpk + gbase;
    auto fr = [&](int t_, int kt_) {
        return *reinterpret_cast<const uint4*>(
            wbp + (((w * 4 + t_) * KT + kt_) * 64 + l) * 4);
    };
    uint4 w00 = fr(0, 0), w01 = fr(0, 1), w10 = fr(1, 0), w11 = fr(1, 1),
          w20 = fr(2, 0), w21 = fr(2, 1), w30 = fr(3, 0), w31 = fr(3, 1);
    pin4(w00); pin4(w01); pin4(w10); pin4(w11);
    pin4(w20); pin4(w21); pin4(w30); pin4(w31);
    uint4 w02 = {}, w03 = {}, w12 = {}, w13 = {},
          w22 = {}, w23 = {}, w32 = {}, w33 = {};
    if (grp != 0) {
        w02 = fr(0, 2); w03 = fr(0, 3); w12 = fr(1, 2); w13 = fr(1, 3);
        w22 = fr(2, 2); w23 = fr(2, 3); w32 = fr(3, 2); w33 = fr(3, 3);
        pin4(w02); pin4(w03); pin4(w12); pin4(w13);
        pin4(w22); pin4(w23); pin4(w32); pin4(w33);
    }

    float bias = 0.f, wih0 = 0.f, wlin_u = 0.f;
    if (grp == 0) { bias = bih0[row] + bhh0[row]; wih0 = Wih0[row]; }
    else if (grp == 1) bias = bih1[row] + bhh1[row];
    else { bias = bih2[row] + bhh2[row]; if (qt == 0) wlin_u = Wlin[u]; }
    const float blin_v = blin[0];

    const int la = (grp == 2) ? 1 : 0;     // first-matvec h source (Wih side)
    const int lb = grp;                    // own-h source (Whh side)
    const uint4* pA[2] = { &hbf[0][la][0], &hbf[1][la][0] };
    const uint4* pB[2] = { &hbf[0][lb][0], &hbf[1][lb][0] };
    _Float16* pW[2] = { (_Float16*)&hbf[0][grp][0] + u, (_Float16*)&hbf[1][grp][0] + u };

    const float s1  = (qt == 2) ? 2.f : 1.f;            // tanh = 2*sigm(2x)-1
    const float o1  = (qt == 2) ? 1.f : 0.f;
    const float ms1 = -s1 * 1.44269504f;                // exp(-s1*g)=exp2(ms1*g)
    float cc = 0.f;                        // cell state (leaders qt==0)

    const f32x4 Z = {0.f, 0.f, 0.f, 0.f};

    __syncthreads();

    auto tick = [&](int T, int rd) {
        const int wr = rd ^ 1;

        // ---- MFMA matvec: D[p,0] = sum_k Wpacked[p,k] * h[k] ----
        const uint4* hA = pA[rd];
        const uint4 b0 = hA[q], b1 = hA[4 + q];
        f32x4 d0 = mm(w00, b0, Z);  f32x4 d1 = mm(w10, b0, Z);
        f32x4 d2 = mm(w20, b0, Z);  f32x4 d3 = mm(w30, b0, Z);
        d0 = mm(w01, b1, d0);  d1 = mm(w11, b1, d1);
        d2 = mm(w21, b1, d2);  d3 = mm(w31, b1, d3);
        if (grp != 0) {
            const uint4* hB = pB[rd];
            const uint4 b2 = hB[q], b3 = hB[4 + q];
            d0 = mm(w02, b2, d0);  d1 = mm(w12, b2, d1);
            d2 = mm(w22, b2, d2);  d3 = mm(w32, b2, d3);
            d0 = mm(w03, b3, d0);  d1 = mm(w13, b3, d1);
            d2 = mm(w23, b3, d2);  d3 = mm(w33, b3, d3);
        }

        // ---- intra-wave gate redistribution (col-0 lanes -> all threads) ----
        if (lz) {
            float* gb = &gbuf[grp][w * 64 + 4 * q];
            *reinterpret_cast<f32x4*>(gb)      = d0;
            *reinterpret_cast<f32x4*>(gb + 16) = d1;
            *reinterpret_cast<f32x4*>(gb + 32) = d2;
            *reinterpret_cast<f32x4*>(gb + 48) = d3;
        }
        float g = gbuf[grp][k] + bias;
        if (grp == 0) g += wih0 * xrow[(T < SQ) ? T : 0];

        // activation + quad combine (DPP)
        const float t   = frcp(1.f + fexp2(ms1 * g));
        const float act = s1 * t - o1;     // sigm for i,f,o; tanh for g
        const float v1 = fdpp<DPP_XOR1>(act);
        const float v2 = fdpp<DPP_XOR2>(act);
        const float v3 = fdpp<DPP_XOR3>(act);

        const int step = T - grp;
        float yv = 0.f;
        if (qt == 0 && step >= 0 && step < SQ) {
            cc = v1 * cc + act * v2;       // sigm(f)*c + sigm(i)*tanh(g)
            float tc = fminf(fmaxf(cc, -15.f), 15.f);
            float e  = fexp2(tc * -2.88539008f);           // exp(-2*tc)
            float h  = v3 * ((1.f - e) * frcp(1.f + e));   // sigm(o)*tanh(c)
            *pW[wr] = (_Float16)h;
            if (grp == 2) yv = wlin_u * h;
            if (step == SQ - 1) {
                out[NB * SQ + grp * NB * HH + b * HH + u] = h;
                out[NB * SQ + 3 * NB * HH + grp * NB * HH + b * HH + u] = cc;
            }
        }
        if (grp == 2) {
            // head partials: quad + row sums (all DPP), 16 slots per buffer
            yv += fdpp<DPP_XOR1>(yv);
            yv += fdpp<DPP_XOR2>(yv);
            yv += fdpp<DPP_ROR4>(yv);
            yv += fdpp<DPP_ROR8>(yv);
            if ((k & 15) == 0) ybuf[rd][k >> 4] = yv;
        }
        if (grp == 0 && u == HH - 1) {
            // final head sum for step T-3 (u==63 quad of grp0 wave 3)
            const int sy = T - 3;
            if (sy >= 0 && sy < SQ) {
                const float4 v = ((const float4*)ybuf[rd ^ 1])[qt];
                float s = (v.x + v.y) + (v.z + v.w);
                s += fdpp<DPP_XOR1>(s);
                s += fdpp<DPP_XOR2>(s);
                if (qt == 3) out[b * SQ + sy] = s + blin_v;
            }
        }
        __syncthreads();
    };

    for (int T = 0; T < SQ + 4; T += 2) {  // ticks 0..4099 (needs 0..4098)
        tick(T, 0);
        tick(T + 1, 1);
    }
}

extern "C" void kernel_launch(void* const* d_in, const int* in_sizes, int n_in,
                              void* d_out, int out_size, void* d_ws, size_t ws_size,
                              hipStream_t stream) {
    const float* x    = (const float*)d_in[0];
    const float* Wih0 = (const float*)d_in[1];
    const float* Whh0 = (const float*)d_in[2];
    const float* bih0 = (const float*)d_in[3];
    const float* bhh0 = (const float*)d_in[4];
    const float* Wih1 = (const float*)d_in[5];
    const float* Whh1 = (const float*)d_in[6];
    const float* bih1 = (const float*)d_in[7];
    const float* bhh1 = (const float*)d_in[8];
    const float* Wih2 = (const float*)d_in[9];
    const float* Whh2 = (const float*)d_in[10];
    const float* bih2 = (const float*)d_in[11];
    const float* bhh2 = (const float*)d_in[12];
    const float* Wlin = (const float*)d_in[13];
    const float* blin = (const float*)d_in[14];
    float* out = (float*)d_out;

    uint32_t* wpk = (uint32_t*)d_ws;   // 40960 u32 = 160 KiB < ws_size
    prep_weights<<<160, 256, 0, stream>>>(Whh0, Wih1, Whh1, Wih2, Whh2, wpk);
    lstm3_fused<<<NB, 768, 0, stream>>>(x, Wih0, bih0, bhh0,
                                        bih1, bhh1, bih2, bhh2,
                                        Wlin, blin, wpk, out);
}

// Round 3
// 2830.304 us; speedup vs baseline: 1.1094x; 1.1094x over previous
//
#include <hip/hip_runtime.h>
#include <stdint.h>

// 3-layer LSTM (H=64, B=256, S=4096, DIN=1) + linear head.
// One block/batch element; 768 thr = 3 groups of 256 (group = layer), skewed
// pipeline (tick T: l0@T, l1@T-1, l2@T-2, y@T-3).
//
// R10: transposed MFMA. R9 (weights=A, h=B) put gate results in D col 0
// (4 lanes/wave) and needed an LDS bounce + DPP butterfly to redistribute --
// that round-trip sat ON the barrier-synced critical path and made ticks
// SLOWER (2025 cyc vs R8's 1695) despite fewer VALU ops. R10 swaps operands:
// h = A operand (row 0 only), weights = B operand. D row 0 = reg 0,
// lanes 0-15: with gate-packing col c -> gate (c>>4)&3 / unit 16w+(c&15),
// lane n of wave w holds ALL FOUR gates of unit 16w+n in the 4 accumulators'
// reg 0. Activation + c/h update run as one 16-lane masked block reading
// d0[0]..d3[0] directly: no gbuf bounce, no DPP butterfly, accvgpr reads
// 16 -> 4. A-frags are broadcast ds_read_b128 (conflict-free); garbage in
// D rows 1-15 is never read.

#define SQ 4096
#define HH 64
#define NB 256

typedef _Float16 h2    __attribute__((ext_vector_type(2)));
typedef _Float16 f16x8 __attribute__((ext_vector_type(8)));
typedef float    f32x4 __attribute__((ext_vector_type(4)));

template<int CTRL>
__device__ __forceinline__ float fdpp(float v) {
    return __builtin_bit_cast(float,
        __builtin_amdgcn_mov_dpp(__builtin_bit_cast(int, v), CTRL, 0xF, 0xF, true));
}
// quad_perm xor1=(1,0,3,2), xor2=(2,3,0,1); row rotates for 16-lane reduce
#define DPP_XOR1 0xB1
#define DPP_XOR2 0x4E
#define DPP_ROR4 0x124
#define DPP_ROR8 0x128

__device__ __forceinline__ float frcp(float x)  { return __builtin_amdgcn_rcpf(x); }
__device__ __forceinline__ float fexp2(float x) { return __builtin_amdgcn_exp2f(x); }

__device__ __forceinline__ void pin4(uint4& r) {
    asm volatile("" : "+v"(r.x), "+v"(r.y), "+v"(r.z), "+v"(r.w));
}
__device__ __forceinline__ void pinf(float& x) { asm volatile("" : "+v"(x)); }

// D = A(h, row 0) x B(weights) + C
__device__ __forceinline__ f32x4 mm(uint4 hv, uint4 wv, f32x4 c) {
    return __builtin_amdgcn_mfma_f32_16x16x32_f16(
        __builtin_bit_cast(f16x8, hv), __builtin_bit_cast(f16x8, wv), c, 0, 0, 0);
}

// ---- prep: fp32 weights -> MFMA B-fragments (packed fp16 pairs).
// Regions: grp0 [0,8192) u32 (Whh0, KT=2); grp1 [8192,24576) ([Wih1|Whh1],
// KT=4); grp2 [24576,40960) ([Wih2|Whh2], KT=4).
// Flat r = (((w*4 + j)*KT + kt)*64 + l)*4 + jj.
// B-frag (wave w, N-tile j, K-tile kt): lane l supplies
//   B[k = (l>>4)*8 + 2jj (+1), n = l&15] = Wcat[orow, k_global]
// where packed col c = 64w+16j+n, orow = 64*j + 16*w + n (gate j of unit
// 16w+n), k_global = 32*kt + krow; k<64 -> Wih cols, k>=64 -> Whh cols.
__global__ __launch_bounds__(256)
void prep_weights(const float* __restrict__ Whh0, const float* __restrict__ Wih1,
                  const float* __restrict__ Whh1, const float* __restrict__ Wih2,
                  const float* __restrict__ Whh2, uint32_t* __restrict__ ws)
{
    const int idx = blockIdx.x * 256 + threadIdx.x;   // 0..40959
    int r, ktbits;
    const float *Wi = nullptr, *Wh;
    if (idx < 8192)       { r = idx;         ktbits = 1; Wh = Whh0; }
    else if (idx < 24576) { r = idx - 8192;  ktbits = 2; Wi = Wih1; Wh = Whh1; }
    else                  { r = idx - 24576; ktbits = 2; Wi = Wih2; Wh = Whh2; }
    const int jj  = r & 3;
    const int l   = (r >> 2) & 63;
    const int rem = r >> 8;
    const int kt  = rem & ((1 << ktbits) - 1);
    const int tw  = rem >> ktbits;
    const int j   = tw & 3;
    const int w   = tw >> 2;
    const int n   = l & 15;
    const int krow = ((l >> 4) << 3) + 2 * jj;
    const int orow = 64 * j + 16 * w + n;
    int kcol = 32 * kt + krow;
    const float* M;
    if (ktbits == 1)    { M = Wh; }
    else if (kcol < 64) { M = Wi; }
    else                { M = Wh; kcol -= 64; }
    h2 t;
    t[0] = (_Float16)M[orow * HH + kcol];
    t[1] = (_Float16)M[orow * HH + kcol + 1];
    ws[idx] = __builtin_bit_cast(uint32_t, t);
}

__global__ __launch_bounds__(768)
__attribute__((amdgpu_waves_per_eu(1, 3)))
void lstm3_fused(
    const float* __restrict__ x,
    const float* __restrict__ Wih0,
    const float* __restrict__ bih0, const float* __restrict__ bhh0,
    const float* __restrict__ bih1, const float* __restrict__ bhh1,
    const float* __restrict__ bih2, const float* __restrict__ bhh2,
    const float* __restrict__ Wlin, const float* __restrict__ blin,
    const uint32_t* __restrict__ wpk,
    float* __restrict__ out)
{
    const int b    = blockIdx.x;
    const int tid  = threadIdx.x;
    const int grp  = tid >> 8;         // layer 0,1,2
    const int k    = tid & 255;
    const int w    = k >> 6;           // wave within group
    const int l    = k & 63;           // lane
    const int n    = l & 15;
    const int q    = l >> 4;           // 16-lane sub-group (A k-slice)
    const bool act16 = (l < 16);       // result-holding lanes
    const int unit = 16 * w + n;       // this lane's hidden unit (if act16)

    __shared__ __align__(16) float xrow[SQ];
    __shared__ __align__(16) uint4 hbf[2][3][8];   // [buf][layer][64 fp16]
    __shared__ __align__(16) float ybuf[2][4];     // per-wave head partials

    for (int i = tid; i < SQ; i += 768) xrow[i] = x[b * SQ + i];
    if (tid < 48) ((uint4*)hbf)[tid] = make_uint4(0, 0, 0, 0);
    if (tid < 8) ((float*)ybuf)[tid] = 0.f;

    // ---- weights: MFMA B-fragments from workspace ----
    const int gbase = (grp == 0) ? 0 : (grp == 1) ? 8192 : 24576;
    const int KT    = (grp == 0) ? 2 : 4;
    const uint32_t* wbp = wpk + gbase;
    auto fr = [&](int j_, int kt_) {
        return *reinterpret_cast<const uint4*>(
            wbp + (((w * 4 + j_) * KT + kt_) * 64 + l) * 4);
    };
    uint4 w00 = fr(0, 0), w01 = fr(0, 1), w10 = fr(1, 0), w11 = fr(1, 1),
          w20 = fr(2, 0), w21 = fr(2, 1), w30 = fr(3, 0), w31 = fr(3, 1);
    pin4(w00); pin4(w01); pin4(w10); pin4(w11);
    pin4(w20); pin4(w21); pin4(w30); pin4(w31);
    uint4 w02 = {}, w03 = {}, w12 = {}, w13 = {},
          w22 = {}, w23 = {}, w32 = {}, w33 = {};
    if (grp != 0) {
        w02 = fr(0, 2); w03 = fr(0, 3); w12 = fr(1, 2); w13 = fr(1, 3);
        w22 = fr(2, 2); w23 = fr(2, 3); w32 = fr(3, 2); w33 = fr(3, 3);
        pin4(w02); pin4(w03); pin4(w12); pin4(w13);
        pin4(w22); pin4(w23); pin4(w32); pin4(w33);
    }

    // ---- per-lane scalars: gate j of unit -> original row 64j + unit ----
    const float* bi = (grp == 0) ? bih0 : (grp == 1) ? bih1 : bih2;
    const float* bh = (grp == 0) ? bhh0 : (grp == 1) ? bhh1 : bhh2;
    float bs0 = bi[unit]       + bh[unit];
    float bs1 = bi[64 + unit]  + bh[64 + unit];
    float bs2 = bi[128 + unit] + bh[128 + unit];
    float bs3 = bi[192 + unit] + bh[192 + unit];
    pinf(bs0); pinf(bs1); pinf(bs2); pinf(bs3);
    float wx0 = 0.f, wx1 = 0.f, wx2 = 0.f, wx3 = 0.f, wl = 0.f;
    if (grp == 0) {
        wx0 = Wih0[unit];       wx1 = Wih0[64 + unit];
        wx2 = Wih0[128 + unit]; wx3 = Wih0[192 + unit];
        pinf(wx0); pinf(wx1); pinf(wx2); pinf(wx3);
    } else if (grp == 2) {
        wl = Wlin[unit]; pinf(wl);
    }
    const float blin_v = blin[0];

    const int la = (grp == 2) ? 1 : 0;     // Wih-side h source layer
    const int lb = grp;                    // Whh-side h source layer (own)
    const uint4* pA[2] = { &hbf[0][la][q], &hbf[1][la][q] };
    const uint4* pB[2] = { &hbf[0][lb][q], &hbf[1][lb][q] };
    _Float16* pH[2] = { (_Float16*)&hbf[0][grp][0] + unit,
                        (_Float16*)&hbf[1][grp][0] + unit };

    const f32x4 Z = {0.f, 0.f, 0.f, 0.f};
    float cc = 0.f;                        // cell state (act16 lanes)

    __syncthreads();

    auto tick = [&](int T, int rd) {
        const int wr = rd ^ 1;

        // ---- MFMA matvec: D[0, c] = sum_k hcat[k] * Wpk[k, c] ----
        const uint4 a0 = pA[rd][0], a1 = pA[rd][4];
        f32x4 d0 = mm(a0, w00, Z);  f32x4 d1 = mm(a0, w10, Z);
        f32x4 d2 = mm(a0, w20, Z);  f32x4 d3 = mm(a0, w30, Z);
        d0 = mm(a1, w01, d0);  d1 = mm(a1, w11, d1);
        d2 = mm(a1, w21, d2);  d3 = mm(a1, w31, d3);
        if (grp != 0) {
            const uint4 c0 = pB[rd][0], c1 = pB[rd][4];
            d0 = mm(c0, w02, d0);  d1 = mm(c0, w12, d1);
            d2 = mm(c0, w22, d2);  d3 = mm(c0, w32, d3);
            d0 = mm(c1, w03, d0);  d1 = mm(c1, w13, d1);
            d2 = mm(c1, w23, d2);  d3 = mm(c1, w33, d3);
        }

        const int step = T - grp;
        float yv = 0.f;
        // ---- 16-lane masked activation + state update (no cross-lane) ----
        if (act16 && step >= 0 && step < SQ) {
            float gi = d0[0] + bs0;
            float gf = d1[0] + bs1;
            float gg = d2[0] + bs2;
            float go = d3[0] + bs3;
            if (grp == 0) {
                const float xT = xrow[T];
                gi += wx0 * xT; gf += wx1 * xT;
                gg += wx2 * xT; go += wx3 * xT;
            }
            const float i_ = frcp(1.f + fexp2(gi * -1.44269504f));
            const float f_ = frcp(1.f + fexp2(gf * -1.44269504f));
            const float o_ = frcp(1.f + fexp2(go * -1.44269504f));
            const float tg = 2.f * frcp(1.f + fexp2(gg * -2.88539008f)) - 1.f;
            cc = f_ * cc + i_ * tg;
            const float tc = fminf(fmaxf(cc, -15.f), 15.f);
            const float e  = fexp2(tc * -2.88539008f);
            const float h  = o_ * ((1.f - e) * frcp(1.f + e));
            pH[wr][0] = (_Float16)h;
            if (grp == 2) yv = wl * h;
            if (step == SQ - 1) {
                out[NB * SQ + grp * NB * HH + b * HH + unit] = h;
                out[NB * SQ + 3 * NB * HH + grp * NB * HH + b * HH + unit] = cc;
            }
        }
        if (grp == 2) {
            // 16-lane head reduce (quad xors + row rotates), lane 0 writes
            yv += fdpp<DPP_XOR1>(yv);
            yv += fdpp<DPP_XOR2>(yv);
            yv += fdpp<DPP_ROR4>(yv);
            yv += fdpp<DPP_ROR8>(yv);
            if (l == 0) ybuf[rd][w] = yv;
        }
        if (grp == 0 && w == 3 && l == 16) {
            // final head sum for step T-3 (idle lane of g0 wave 3)
            const int sy = T - 3;
            if (sy >= 0 && sy < SQ) {
                const float4 v = *(const float4*)ybuf[rd ^ 1];
                out[b * SQ + sy] = (v.x + v.y) + (v.z + v.w) + blin_v;
            }
        }
        __syncthreads();
    };

    for (int T = 0; T < SQ + 4; T += 2) {  // ticks 0..4099 (needs 0..4098)
        tick(T, 0);
        tick(T + 1, 1);
    }
}

extern "C" void kernel_launch(void* const* d_in, const int* in_sizes, int n_in,
                              void* d_out, int out_size, void* d_ws, size_t ws_size,
                              hipStream_t stream) {
    const float* x    = (const float*)d_in[0];
    const float* Wih0 = (const float*)d_in[1];
    const float* Whh0 = (const float*)d_in[2];
    const float* bih0 = (const float*)d_in[3];
    const float* bhh0 = (const float*)d_in[4];
    const float* Wih1 = (const float*)d_in[5];
    const float* Whh1 = (const float*)d_in[6];
    const float* bih1 = (const float*)d_in[7];
    const float* bhh1 = (const float*)d_in[8];
    const float* Wih2 = (const float*)d_in[9];
    const float* Whh2 = (const float*)d_in[10];
    const float* bih2 = (const float*)d_in[11];
    const float* bhh2 = (const float*)d_in[12];
    const float* Wlin = (const float*)d_in[13];
    const float* blin = (const float*)d_in[14];
    float* out = (float*)d_out;

    uint32_t* wpk = (uint32_t*)d_ws;   // 40960 u32 = 160 KiB < ws_size
    prep_weights<<<160, 256, 0, stream>>>(Whh0, Wih1, Whh1, Wih2, Whh2, wpk);
    lstm3_fused<<<NB, 768, 0, stream>>>(x, Wih0, bih0, bhh0,
                                        bih1, bhh1, bih2, bhh2,
                                        Wlin, blin, wpk, out);
}

// Round 4
// 2616.321 us; speedup vs baseline: 1.2001x; 1.0818x over previous
//
#include <hip/hip_runtime.h>
#include <stdint.h>

// 3-layer LSTM (H=64, B=256, S=4096, DIN=1) + linear head.
// One block/batch element; 768 thr = 3 groups of 256 (group = layer), skewed
// pipeline (tick T: l0@T, l1@T-1, l2@T-2, y@T-3).
//
// R11: exploit D-row replication. The A operand (h) is loaded broadcast per
// 16-lane group, so ALL rows of A equal h -> every D row is identical ->
// every lane holds all 4 gates of unit 16w+(l&15). Three consequences:
// (1) bias lives in persistent pinned C-operand regs (MFMA reads C, writes
//     separate D) -> 16 zero-movs + 4 bias adds deleted per tick;
// (2) activation runs unmasked on all 64 lanes under a wave-UNIFORM step
//     guard (redundant but free) -> no divergent exec juggling; only the
//     tiny l<16 LDS write stays masked;
// (3) the linear head y = Wlin . h2 is just one more MFMA output column on
//     grp2-wave0 (B-frag col0 = Wlin over the Whh2 K-range, C = blin):
//     2 extra MFMAs replace the DPP head reduce on 4 waves + grp0 tail sum.

#define SQ 4096
#define HH 64
#define NB 256

typedef _Float16 h2    __attribute__((ext_vector_type(2)));
typedef _Float16 f16x8 __attribute__((ext_vector_type(8)));
typedef float    f32x4 __attribute__((ext_vector_type(4)));

__device__ __forceinline__ float frcp(float x)  { return __builtin_amdgcn_rcpf(x); }
__device__ __forceinline__ float fexp2(float x) { return __builtin_amdgcn_exp2f(x); }

__device__ __forceinline__ void pin4(uint4& r) {
    asm volatile("" : "+v"(r.x), "+v"(r.y), "+v"(r.z), "+v"(r.w));
}
__device__ __forceinline__ void pinv(f32x4& r) {
    float t0 = r[0], t1 = r[1], t2 = r[2], t3 = r[3];
    asm volatile("" : "+v"(t0), "+v"(t1), "+v"(t2), "+v"(t3));
    r[0] = t0; r[1] = t1; r[2] = t2; r[3] = t3;
}

// D = A(h, rows replicated) x B(weights) + C
__device__ __forceinline__ f32x4 mm(uint4 hv, uint4 wv, f32x4 c) {
    return __builtin_amdgcn_mfma_f32_16x16x32_f16(
        __builtin_bit_cast(f16x8, hv), __builtin_bit_cast(f16x8, wv), c, 0, 0, 0);
}

// ---- prep: fp32 weights -> MFMA B-fragments (packed fp16 pairs).
// Regions: grp0 [0,8192) u32 (Whh0, KT=2); grp1 [8192,24576) ([Wih1|Whh1],
// KT=4); grp2 [24576,40960) ([Wih2|Whh2], KT=4); y-frag [40960,41472):
// 2 K-tiles (h2 range), col0 = Wlin, cols 1-15 = 0.
// Flat r = (((w*4 + j)*KT + kt)*64 + l)*4 + jj.
// B-frag: lane l supplies B[k = (l>>4)*8 + 2jj (+1), n = l&15] = Wcat[orow,
// k_global], orow = 64*j + 16*w + n (gate j of unit 16w+n),
// k_global = 32*kt + krow; k<64 -> Wih cols, k>=64 -> Whh cols.
__global__ __launch_bounds__(256)
void prep_weights(const float* __restrict__ Whh0, const float* __restrict__ Wih1,
                  const float* __restrict__ Whh1, const float* __restrict__ Wih2,
                  const float* __restrict__ Whh2, const float* __restrict__ Wlin,
                  uint32_t* __restrict__ ws)
{
    const int idx = blockIdx.x * 256 + threadIdx.x;   // 0..41471
    if (idx >= 40960) {                               // y-fragment region
        const int r  = idx - 40960;
        const int jj = r & 3;
        const int l  = (r >> 2) & 63;
        const int kk = (r >> 8) & 1;                  // 0 -> kt2, 1 -> kt3
        const int n  = l & 15;
        const int krow = ((l >> 4) << 3) + 2 * jj;
        const int ku   = 32 * kk + krow;              // h2 unit index
        h2 t;
        t[0] = (_Float16)((n == 0) ? Wlin[ku]     : 0.f);
        t[1] = (_Float16)((n == 0) ? Wlin[ku + 1] : 0.f);
        ws[idx] = __builtin_bit_cast(uint32_t, t);
        return;
    }
    int r, ktbits;
    const float *Wi = nullptr, *Wh;
    if (idx < 8192)       { r = idx;         ktbits = 1; Wh = Whh0; }
    else if (idx < 24576) { r = idx - 8192;  ktbits = 2; Wi = Wih1; Wh = Whh1; }
    else                  { r = idx - 24576; ktbits = 2; Wi = Wih2; Wh = Whh2; }
    const int jj  = r & 3;
    const int l   = (r >> 2) & 63;
    const int rem = r >> 8;
    const int kt  = rem & ((1 << ktbits) - 1);
    const int tw  = rem >> ktbits;
    const int j   = tw & 3;
    const int w   = tw >> 2;
    const int n   = l & 15;
    const int krow = ((l >> 4) << 3) + 2 * jj;
    const int orow = 64 * j + 16 * w + n;
    int kcol = 32 * kt + krow;
    const float* M;
    if (ktbits == 1)    { M = Wh; }
    else if (kcol < 64) { M = Wi; }
    else                { M = Wh; kcol -= 64; }
    h2 t;
    t[0] = (_Float16)M[orow * HH + kcol];
    t[1] = (_Float16)M[orow * HH + kcol + 1];
    ws[idx] = __builtin_bit_cast(uint32_t, t);
}

__global__ __launch_bounds__(768)
__attribute__((amdgpu_waves_per_eu(1, 3)))
void lstm3_fused(
    const float* __restrict__ x,
    const float* __restrict__ Wih0,
    const float* __restrict__ bih0, const float* __restrict__ bhh0,
    const float* __restrict__ bih1, const float* __restrict__ bhh1,
    const float* __restrict__ bih2, const float* __restrict__ bhh2,
    const float* __restrict__ blin,
    const uint32_t* __restrict__ wpk,
    float* __restrict__ out)
{
    const int b    = blockIdx.x;
    const int tid  = threadIdx.x;
    const int grp  = tid >> 8;         // layer 0,1,2
    const int k    = tid & 255;
    const int w    = k >> 6;           // wave within group
    const int l    = k & 63;           // lane
    const int n    = l & 15;
    const int q    = l >> 4;           // 16-lane sub-group (A k-slice)
    const int unit = 16 * w + n;       // this lane's hidden unit
    const bool grp2w0 = (grp == 2) && (w == 0);

    __shared__ __align__(16) float xrow[SQ];
    __shared__ __align__(16) uint4 hbf[2][3][8];   // [buf][layer][64 fp16]

    for (int i = tid; i < SQ; i += 768) xrow[i] = x[b * SQ + i];
    if (tid < 48) ((uint4*)hbf)[tid] = make_uint4(0, 0, 0, 0);

    // ---- weights: MFMA B-fragments from workspace ----
    const int gbase = (grp == 0) ? 0 : (grp == 1) ? 8192 : 24576;
    const int KT    = (grp == 0) ? 2 : 4;
    const uint32_t* wbp = wpk + gbase;
    auto fr = [&](int j_, int kt_) {
        return *reinterpret_cast<const uint4*>(
            wbp + (((w * 4 + j_) * KT + kt_) * 64 + l) * 4);
    };
    uint4 w00 = fr(0, 0), w01 = fr(0, 1), w10 = fr(1, 0), w11 = fr(1, 1),
          w20 = fr(2, 0), w21 = fr(2, 1), w30 = fr(3, 0), w31 = fr(3, 1);
    pin4(w00); pin4(w01); pin4(w10); pin4(w11);
    pin4(w20); pin4(w21); pin4(w30); pin4(w31);
    uint4 w02 = {}, w03 = {}, w12 = {}, w13 = {},
          w22 = {}, w23 = {}, w32 = {}, w33 = {};
    if (grp != 0) {
        w02 = fr(0, 2); w03 = fr(0, 3); w12 = fr(1, 2); w13 = fr(1, 3);
        w22 = fr(2, 2); w23 = fr(2, 3); w32 = fr(3, 2); w33 = fr(3, 3);
        pin4(w02); pin4(w03); pin4(w12); pin4(w13);
        pin4(w22); pin4(w23); pin4(w32); pin4(w33);
    }
    uint4 wy2 = {}, wy3 = {};
    f32x4 cy = {0.f, 0.f, 0.f, 0.f};
    if (grp2w0) {
        wy2 = *reinterpret_cast<const uint4*>(wpk + 40960 + (0 * 64 + l) * 4);
        wy3 = *reinterpret_cast<const uint4*>(wpk + 40960 + (1 * 64 + l) * 4);
        pin4(wy2); pin4(wy3);
        const float bv = blin[0];
        cy = f32x4{bv, bv, bv, bv};
        pinv(cy);
    }

    // ---- persistent bias C-operands (gate j of unit -> row 64j + unit) ----
    const float* bi = (grp == 0) ? bih0 : (grp == 1) ? bih1 : bih2;
    const float* bh = (grp == 0) ? bhh0 : (grp == 1) ? bhh1 : bhh2;
    const float bs0 = bi[unit]       + bh[unit];
    const float bs1 = bi[64 + unit]  + bh[64 + unit];
    const float bs2 = bi[128 + unit] + bh[128 + unit];
    const float bs3 = bi[192 + unit] + bh[192 + unit];
    f32x4 cb0 = {bs0, bs0, bs0, bs0};  pinv(cb0);
    f32x4 cb1 = {bs1, bs1, bs1, bs1};  pinv(cb1);
    f32x4 cb2 = {bs2, bs2, bs2, bs2};  pinv(cb2);
    f32x4 cb3 = {bs3, bs3, bs3, bs3};  pinv(cb3);

    float wx0 = 0.f, wx1 = 0.f, wx2 = 0.f, wx3 = 0.f;
    if (grp == 0) {
        wx0 = Wih0[unit];       wx1 = Wih0[64 + unit];
        wx2 = Wih0[128 + unit]; wx3 = Wih0[192 + unit];
    }

    const int la = (grp == 2) ? 1 : 0;     // Wih-side h source layer
    const int lb = grp;                    // Whh-side h source layer (own)
    const uint4* pA[2] = { &hbf[0][la][q], &hbf[1][la][q] };
    const uint4* pB[2] = { &hbf[0][lb][q], &hbf[1][lb][q] };
    _Float16* pH[2] = { (_Float16*)&hbf[0][grp][0] + unit,
                        (_Float16*)&hbf[1][grp][0] + unit };

    float cc = 0.f;                        // cell state (replicated all lanes)

    __syncthreads();

    auto tick = [&](int T, int rd) {
        const int wr = rd ^ 1;
        float xT = 0.f;
        if (grp == 0) xT = xrow[(T < SQ) ? T : 0];   // early issue, broadcast

        // ---- MFMA matvec: D[., c] = sum_k hcat[k] * Wpk[k, c] + bias ----
        const uint4 a0 = pA[rd][0], a1 = pA[rd][4];
        f32x4 d0 = mm(a0, w00, cb0);
        f32x4 d1 = mm(a0, w10, cb1);
        f32x4 d2 = mm(a0, w20, cb2);
        f32x4 d3 = mm(a0, w30, cb3);
        d0 = mm(a1, w01, d0);  d1 = mm(a1, w11, d1);
        d2 = mm(a1, w21, d2);  d3 = mm(a1, w31, d3);
        if (grp != 0) {
            const uint4 c0 = pB[rd][0], c1 = pB[rd][4];
            d0 = mm(c0, w02, d0);  d1 = mm(c0, w12, d1);
            d2 = mm(c0, w22, d2);  d3 = mm(c0, w32, d3);
            d0 = mm(c1, w03, d0);  d1 = mm(c1, w13, d1);
            d2 = mm(c1, w23, d2);  d3 = mm(c1, w33, d3);
            if (grp2w0) {
                // head: y_{T-3} = Wlin . h2_{T-3} + blin via 2 extra MFMAs
                f32x4 d4 = mm(c0, wy2, cy);
                d4 = mm(c1, wy3, d4);
                const int sy = T - 3;
                if (l == 0 && sy >= 0 && sy < SQ)
                    out[b * SQ + sy] = d4[0];
            }
        }

        const int step = T - grp;
        if (step >= 0 && step < SQ) {      // wave-uniform guard
            // all 64 lanes redundantly process unit 16w+n (D rows replicated)
            float gi = d0[0], gf = d1[0], gg = d2[0], go = d3[0];
            if (grp == 0) {
                gi += wx0 * xT; gf += wx1 * xT;
                gg += wx2 * xT; go += wx3 * xT;
            }
            const float i_ = frcp(1.f + fexp2(gi * -1.44269504f));
            const float f_ = frcp(1.f + fexp2(gf * -1.44269504f));
            const float o_ = frcp(1.f + fexp2(go * -1.44269504f));
            const float tg = 2.f * frcp(1.f + fexp2(gg * -2.88539008f)) - 1.f;
            cc = f_ * cc + i_ * tg;
            const float tc = fminf(fmaxf(cc, -15.f), 15.f);
            const float e  = fexp2(tc * -2.88539008f);
            const float h  = o_ * ((1.f - e) * frcp(1.f + e));
            if (l < 16) {
                pH[wr][0] = (_Float16)h;
                if (step == SQ - 1) {
                    out[NB * SQ + grp * NB * HH + b * HH + unit] = h;
                    out[NB * SQ + 3 * NB * HH + grp * NB * HH + b * HH + unit] = cc;
                }
            }
        }
        __syncthreads();
    };

    for (int T = 0; T < SQ + 4; T += 2) {  // ticks 0..4099 (needs 0..4098)
        tick(T, 0);
        tick(T + 1, 1);
    }
}

extern "C" void kernel_launch(void* const* d_in, const int* in_sizes, int n_in,
                              void* d_out, int out_size, void* d_ws, size_t ws_size,
                              hipStream_t stream) {
    const float* x    = (const float*)d_in[0];
    const float* Wih0 = (const float*)d_in[1];
    const float* Whh0 = (const float*)d_in[2];
    const float* bih0 = (const float*)d_in[3];
    const float* bhh0 = (const float*)d_in[4];
    const float* Wih1 = (const float*)d_in[5];
    const float* Whh1 = (const float*)d_in[6];
    const float* bih1 = (const float*)d_in[7];
    const float* bhh1 = (const float*)d_in[8];
    const float* Wih2 = (const float*)d_in[9];
    const float* Whh2 = (const float*)d_in[10];
    const float* bih2 = (const float*)d_in[11];
    const float* bhh2 = (const float*)d_in[12];
    const float* Wlin = (const float*)d_in[13];
    const float* blin = (const float*)d_in[14];
    float* out = (float*)d_out;

    uint32_t* wpk = (uint32_t*)d_ws;   // 41472 u32 = 162 KiB < ws_size
    prep_weights<<<162, 256, 0, stream>>>(Whh0, Wih1, Whh1, Wih2, Whh2, Wlin, wpk);
    lstm3_fused<<<NB, 768, 0, stream>>>(x, Wih0, bih0, bhh0,
                                        bih1, bhh1, bih2, bhh2,
                                        blin, wpk, out);
}

// Round 7
// 2579.626 us; speedup vs baseline: 1.2172x; 1.0142x over previous
//
#include <hip/hip_runtime.h>
#include <stdint.h>

// 3-layer LSTM (H=64, B=256, S=4096, DIN=1) + linear head.
// One block/batch element; 768 thr = 3 groups of 256 (group = layer), skewed
// pipeline (tick T: l0@T, l1@T-1, l2@T-2, y@T-3).
//
// R12c: kill the per-tick global-store drain. R11's y-head stored 1 float to
// HBM every tick from grp2w0; __syncthreads = s_waitcnt vmcnt(0)+s_barrier,
// so EVERY tick's barrier waited ~200-300cy for an L2 store ack, on the
// heaviest wave (18 MFMAs). Fixes:
// (1) y staged per-tick into a 32-float LDS buffer (ds_write_b32, already
//     covered by the barrier's lgkmcnt(0) -- zero marginal drain); ONE
//     coalesced 128B global store per 32 ticks. (v_writelane needs 2
//     constant-bus SGPR reads -> not encodable; LDS route instead.)
// (2) head's 2 MFMAs moved grp2w0 -> grp0w1 (8 own MFMAs, lightest wave).
//     Legal: head reads h2_{T-3} from the PUBLISHED buffer hbf[rd][2]
//     (current tick writes only rd^1) -> fully off the recurrence path.
// (3) xrow padded +4 zeros -> (T<SQ) cndmask deleted.
// Carried: h=A-operand row-replicated MFMA (all lanes hold all 4 gates of
// unit 16w+(l&15)); bias in persistent C regs; unmasked activation.

#define SQ 4096
#define HH 64
#define NB 256

typedef _Float16 h2    __attribute__((ext_vector_type(2)));
typedef _Float16 f16x8 __attribute__((ext_vector_type(8)));
typedef float    f32x4 __attribute__((ext_vector_type(4)));

__device__ __forceinline__ float frcp(float x)  { return __builtin_amdgcn_rcpf(x); }
__device__ __forceinline__ float fexp2(float x) { return __builtin_amdgcn_exp2f(x); }

__device__ __forceinline__ void pin4(uint4& r) {
    asm volatile("" : "+v"(r.x), "+v"(r.y), "+v"(r.z), "+v"(r.w));
}
__device__ __forceinline__ void pinv(f32x4& r) {
    float t0 = r[0], t1 = r[1], t2 = r[2], t3 = r[3];
    asm volatile("" : "+v"(t0), "+v"(t1), "+v"(t2), "+v"(t3));
    r[0] = t0; r[1] = t1; r[2] = t2; r[3] = t3;
}

// D = A(h, rows replicated) x B(weights) + C
__device__ __forceinline__ f32x4 mm(uint4 hv, uint4 wv, f32x4 c) {
    return __builtin_amdgcn_mfma_f32_16x16x32_f16(
        __builtin_bit_cast(f16x8, hv), __builtin_bit_cast(f16x8, wv), c, 0, 0, 0);
}

// ---- prep: fp32 weights -> MFMA B-fragments (packed fp16 pairs).
// Regions: grp0 [0,8192) u32 (Whh0, KT=2); grp1 [8192,24576) ([Wih1|Whh1],
// KT=4); grp2 [24576,40960) ([Wih2|Whh2], KT=4); y-frag [40960,41472):
// 2 K-tiles (h2 range), col0 = Wlin, cols 1-15 = 0.
// Flat r = (((w*4 + j)*KT + kt)*64 + l)*4 + jj.
// B-frag: lane l supplies B[k = (l>>4)*8 + 2jj (+1), n = l&15] = Wcat[orow,
// k_global], orow = 64*j + 16*w + n (gate j of unit 16w+n),
// k_global = 32*kt + krow; k<64 -> Wih cols, k>=64 -> Whh cols.
__global__ __launch_bounds__(256)
void prep_weights(const float* __restrict__ Whh0, const float* __restrict__ Wih1,
                  const float* __restrict__ Whh1, const float* __restrict__ Wih2,
                  const float* __restrict__ Whh2, const float* __restrict__ Wlin,
                  uint32_t* __restrict__ ws)
{
    const int idx = blockIdx.x * 256 + threadIdx.x;   // 0..41471
    if (idx >= 40960) {                               // y-fragment region
        const int r  = idx - 40960;
        const int jj = r & 3;
        const int l  = (r >> 2) & 63;
        const int kk = (r >> 8) & 1;                  // 0 -> kt2, 1 -> kt3
        const int n  = l & 15;
        const int krow = ((l >> 4) << 3) + 2 * jj;
        const int ku   = 32 * kk + krow;              // h2 unit index
        h2 t;
        t[0] = (_Float16)((n == 0) ? Wlin[ku]     : 0.f);
        t[1] = (_Float16)((n == 0) ? Wlin[ku + 1] : 0.f);
        ws[idx] = __builtin_bit_cast(uint32_t, t);
        return;
    }
    int r, ktbits;
    const float *Wi = nullptr, *Wh;
    if (idx < 8192)       { r = idx;         ktbits = 1; Wh = Whh0; }
    else if (idx < 24576) { r = idx - 8192;  ktbits = 2; Wi = Wih1; Wh = Whh1; }
    else                  { r = idx - 24576; ktbits = 2; Wi = Wih2; Wh = Whh2; }
    const int jj  = r & 3;
    const int l   = (r >> 2) & 63;
    const int rem = r >> 8;
    const int kt  = rem & ((1 << ktbits) - 1);
    const int tw  = rem >> ktbits;
    const int j   = tw & 3;
    const int w   = tw >> 2;
    const int n   = l & 15;
    const int krow = ((l >> 4) << 3) + 2 * jj;
    const int orow = 64 * j + 16 * w + n;
    int kcol = 32 * kt + krow;
    const float* M;
    if (ktbits == 1)    { M = Wh; }
    else if (kcol < 64) { M = Wi; }
    else                { M = Wh; kcol -= 64; }
    h2 t;
    t[0] = (_Float16)M[orow * HH + kcol];
    t[1] = (_Float16)M[orow * HH + kcol + 1];
    ws[idx] = __builtin_bit_cast(uint32_t, t);
}

__global__ __launch_bounds__(768)
__attribute__((amdgpu_waves_per_eu(1, 3)))
void lstm3_fused(
    const float* __restrict__ x,
    const float* __restrict__ Wih0,
    const float* __restrict__ bih0, const float* __restrict__ bhh0,
    const float* __restrict__ bih1, const float* __restrict__ bhh1,
    const float* __restrict__ bih2, const float* __restrict__ bhh2,
    const float* __restrict__ blin,
    const uint32_t* __restrict__ wpk,
    float* __restrict__ out)
{
    const int b    = blockIdx.x;
    const int tid  = threadIdx.x;
    const int grp  = tid >> 8;         // layer 0,1,2
    const int k    = tid & 255;
    const int w    = k >> 6;           // wave within group
    const int l    = k & 63;           // lane
    const int n    = l & 15;
    const int q    = l >> 4;           // 16-lane sub-group (A k-slice)
    const int unit = 16 * w + n;       // this lane's hidden unit
    const bool grp0w1 = (grp == 0) && (w == 1);   // head wave

    __shared__ __align__(16) float xrow[SQ + 4];
    __shared__ __align__(16) uint4 hbf[2][3][8];   // [buf][layer][64 fp16]
    __shared__ __align__(16) float ystage[32];     // head staging (1 wave)

    for (int i = tid; i < SQ; i += 768) xrow[i] = x[b * SQ + i];
    if (tid < 4) xrow[SQ + tid] = 0.f;
    if (tid < 48) ((uint4*)hbf)[tid] = make_uint4(0, 0, 0, 0);

    // ---- weights: MFMA B-fragments from workspace ----
    const int gbase = (grp == 0) ? 0 : (grp == 1) ? 8192 : 24576;
    const int KT    = (grp == 0) ? 2 : 4;
    const uint32_t* wbp = wpk + gbase;
    auto fr = [&](int j_, int kt_) {
        return *reinterpret_cast<const uint4*>(
            wbp + (((w * 4 + j_) * KT + kt_) * 64 + l) * 4);
    };
    uint4 w00 = fr(0, 0), w01 = fr(0, 1), w10 = fr(1, 0), w11 = fr(1, 1),
          w20 = fr(2, 0), w21 = fr(2, 1), w30 = fr(3, 0), w31 = fr(3, 1);
    pin4(w00); pin4(w01); pin4(w10); pin4(w11);
    pin4(w20); pin4(w21); pin4(w30); pin4(w31);
    uint4 w02 = {}, w03 = {}, w12 = {}, w13 = {},
          w22 = {}, w23 = {}, w32 = {}, w33 = {};
    if (grp != 0) {
        w02 = fr(0, 2); w03 = fr(0, 3); w12 = fr(1, 2); w13 = fr(1, 3);
        w22 = fr(2, 2); w23 = fr(2, 3); w32 = fr(3, 2); w33 = fr(3, 3);
        pin4(w02); pin4(w03); pin4(w12); pin4(w13);
        pin4(w22); pin4(w23); pin4(w32); pin4(w33);
    }
    // head fragments (grp0w1 only)
    uint4 wy2 = {}, wy3 = {};
    f32x4 cy = {0.f, 0.f, 0.f, 0.f};
    if (grp0w1) {
        wy2 = *reinterpret_cast<const uint4*>(wpk + 40960 + (0 * 64 + l) * 4);
        wy3 = *reinterpret_cast<const uint4*>(wpk + 40960 + (1 * 64 + l) * 4);
        pin4(wy2); pin4(wy3);
        const float bv = blin[0];
        cy = f32x4{bv, bv, bv, bv};
        pinv(cy);
    }

    // ---- persistent bias C-operands (gate j of unit -> row 64j + unit) ----
    const float* bi = (grp == 0) ? bih0 : (grp == 1) ? bih1 : bih2;
    const float* bh = (grp == 0) ? bhh0 : (grp == 1) ? bhh1 : bhh2;
    const float bs0 = bi[unit]       + bh[unit];
    const float bs1 = bi[64 + unit]  + bh[64 + unit];
    const float bs2 = bi[128 + unit] + bh[128 + unit];
    const float bs3 = bi[192 + unit] + bh[192 + unit];
    f32x4 cb0 = {bs0, bs0, bs0, bs0};  pinv(cb0);
    f32x4 cb1 = {bs1, bs1, bs1, bs1};  pinv(cb1);
    f32x4 cb2 = {bs2, bs2, bs2, bs2};  pinv(cb2);
    f32x4 cb3 = {bs3, bs3, bs3, bs3};  pinv(cb3);

    float wx0 = 0.f, wx1 = 0.f, wx2 = 0.f, wx3 = 0.f;
    if (grp == 0) {
        wx0 = Wih0[unit];       wx1 = Wih0[64 + unit];
        wx2 = Wih0[128 + unit]; wx3 = Wih0[192 + unit];
    }

    const int la = (grp == 2) ? 1 : 0;     // Wih-side h source layer
    const int lb = grp;                    // Whh-side h source layer (own)
    const uint4* pA[2] = { &hbf[0][la][q], &hbf[1][la][q] };
    const uint4* pB[2] = { &hbf[0][lb][q], &hbf[1][lb][q] };
    const uint4* pY[2] = { &hbf[0][2][q],  &hbf[1][2][q] };   // head source
    _Float16* pH[2] = { (_Float16*)&hbf[0][grp][0] + unit,
                        (_Float16*)&hbf[1][grp][0] + unit };

    float cc = 0.f;                        // cell state (replicated all lanes)

    __syncthreads();

    auto tick = [&](int T, int rd) {
        const int wr = rd ^ 1;
        float xT = 0.f;
        if (grp == 0) xT = xrow[T];        // padded; broadcast read

        // ---- MFMA matvec: D[., c] = sum_k hcat[k] * Wpk[k, c] + bias ----
        const uint4 a0 = pA[rd][0], a1 = pA[rd][4];
        f32x4 d0 = mm(a0, w00, cb0);
        f32x4 d1 = mm(a0, w10, cb1);
        f32x4 d2 = mm(a0, w20, cb2);
        f32x4 d3 = mm(a0, w30, cb3);
        d0 = mm(a1, w01, d0);  d1 = mm(a1, w11, d1);
        d2 = mm(a1, w21, d2);  d3 = mm(a1, w31, d3);
        if (grp != 0) {
            const uint4 c0 = pB[rd][0], c1 = pB[rd][4];
            d0 = mm(c0, w02, d0);  d1 = mm(c0, w12, d1);
            d2 = mm(c0, w22, d2);  d3 = mm(c0, w32, d3);
            d0 = mm(c1, w03, d0);  d1 = mm(c1, w13, d1);
            d2 = mm(c1, w23, d2);  d3 = mm(c1, w33, d3);
        }

        if (grp0w1) {
            // head: y_{T-3} = Wlin . h2_{T-3} + blin; h2_{T-3} is in the
            // PUBLISHED buffer hbf[rd][2] (this tick writes only rd^1).
            const int sy = T - 3;
            if (sy >= 0 && sy < SQ) {
                const uint4 y0 = pY[rd][0], y1 = pY[rd][4];
                f32x4 d4 = mm(y0, wy2, cy);
                d4 = mm(y1, wy3, d4);
                if (l == 0) ystage[sy & 31] = d4[0];   // ds_write, lgkm-only
                if ((sy & 31) == 31) {
                    // flush: same wave wrote all 32 slots; intra-wave LDS
                    // ordering handled by compiler-inserted lgkmcnt waits
                    const float yv = ystage[l & 31];
                    if (l < 32) out[b * SQ + (sy - 31) + l] = yv;
                }
            }
        }

        const int step = T - grp;
        if (step >= 0 && step < SQ) {      // wave-uniform guard
            // all 64 lanes redundantly process unit 16w+n (D rows replicated)
            float gi = d0[0], gf = d1[0], gg = d2[0], go = d3[0];
            if (grp == 0) {
                gi += wx0 * xT; gf += wx1 * xT;
                gg += wx2 * xT; go += wx3 * xT;
            }
            const float i_ = frcp(1.f + fexp2(gi * -1.44269504f));
            const float f_ = frcp(1.f + fexp2(gf * -1.44269504f));
            const float o_ = frcp(1.f + fexp2(go * -1.44269504f));
            const float tg = 2.f * frcp(1.f + fexp2(gg * -2.88539008f)) - 1.f;
            cc = f_ * cc + i_ * tg;
            const float tc = fminf(fmaxf(cc, -15.f), 15.f);
            const float e  = fexp2(tc * -2.88539008f);
            const float h  = o_ * ((1.f - e) * frcp(1.f + e));
            if (l < 16) {
                pH[wr][0] = (_Float16)h;
                if (step == SQ - 1) {
                    out[NB * SQ + grp * NB * HH + b * HH + unit] = h;
                    out[NB * SQ + 3 * NB * HH + grp * NB * HH + b * HH + unit] = cc;
                }
            }
        }
        __syncthreads();
    };

    for (int T = 0; T < SQ + 4; T += 2) {  // ticks 0..4099 (needs 0..4098)
        tick(T, 0);
        tick(T + 1, 1);
    }
}

extern "C" void kernel_launch(void* const* d_in, const int* in_sizes, int n_in,
                              void* d_out, int out_size, void* d_ws, size_t ws_size,
                              hipStream_t stream) {
    const float* x    = (const float*)d_in[0];
    const float* Wih0 = (const float*)d_in[1];
    const float* Whh0 = (const float*)d_in[2];
    const float* bih0 = (const float*)d_in[3];
    const float* bhh0 = (const float*)d_in[4];
    const float* Wih1 = (const float*)d_in[5];
    const float* Whh1 = (const float*)d_in[6];
    const float* bih1 = (const float*)d_in[7];
    const float* bhh1 = (const float*)d_in[8];
    const float* Wih2 = (const float*)d_in[9];
    const float* Whh2 = (const float*)d_in[10];
    const float* bih2 = (const float*)d_in[11];
    const float* bhh2 = (const float*)d_in[12];
    const float* Wlin = (const float*)d_in[13];
    const float* blin = (const float*)d_in[14];
    float* out = (float*)d_out;

    uint32_t* wpk = (uint32_t*)d_ws;   // 41472 u32 = 162 KiB < ws_size
    prep_weights<<<162, 256, 0, stream>>>(Whh0, Wih1, Whh1, Wih2, Whh2, Wlin, wpk);
    lstm3_fused<<<NB, 768, 0, stream>>>(x, Wih0, bih0, bhh0,
                                        bih1, bhh1, bih2, bhh2,
                                        blin, wpk, out);
}